// Round 2
// baseline (619.224 us; speedup 1.0000x reference)
//
#include <hip/hip_runtime.h>
#include <stdint.h>

// Problem constants: B=256, T=128, D=256, H=8, AE=32, DFF=512
#define DEVI static __device__ __forceinline__

typedef __attribute__((ext_vector_type(4))) float f32x4;
typedef __attribute__((ext_vector_type(8))) short bf8;     // 8 bf16 as shorts (MFMA A/B frag)
typedef __attribute__((ext_vector_type(4))) unsigned short u16x4;

DEVI unsigned short f2bf(float f) {
  unsigned u = __builtin_bit_cast(unsigned, f);
  u = (u + 0x7FFFu + ((u >> 16) & 1u)) >> 16;
  return (unsigned short)u;
}
DEVI float bf2f(unsigned short s) {
  return __builtin_bit_cast(float, ((unsigned)s) << 16);
}
// LDS XOR swizzle: reads (row=lane&15) are 2-way (free); transposed staging writes ~4-way.
DEVI int swz(int row) { return (((row >> 2) ^ row) & 7) << 4; }

// ---------------------------------------------------------------------------
// Generic per-t batched GEMM: C[b,t,n] = sum_k A[b,t,k] * W[t,k,n]
// A bf16 (B,128,Ka); W fp32 (128,Ka,N) converted to bf16 during staging.
// BM=256 (whole batch -> each weight element fetched once), BN=128, BK=64.
// ---------------------------------------------------------------------------
template<bool OUT_BF16>
__global__ __launch_bounds__(256)
void gemm_tk(const unsigned short* __restrict__ A, const float* __restrict__ W,
             void* __restrict__ C, int Ka, int N)
{
  const int t = blockIdx.y;
  const int n0blk = blockIdx.x * 128;
  const int tid = threadIdx.x;
  const int lane = tid & 63;
  const int wv = tid >> 6;
  const int wrow = wv * 64;

  __shared__ short As[256 * 64];  // [m][k] swizzled, 32KB
  __shared__ short Ws[128 * 64];  // [n][k] swizzled (W^T), 16KB

  f32x4 acc[4][8];
#pragma unroll
  for (int i = 0; i < 4; ++i)
#pragma unroll
    for (int j = 0; j < 8; ++j) acc[i][j] = f32x4{0.f, 0.f, 0.f, 0.f};

  const long ldA = 128L * Ka;
  const unsigned short* Ab = A + (long)t * Ka;
  const float* Wb = W + (long)t * Ka * N + n0blk;

  for (int kt = 0; kt < Ka; kt += 64) {
    // stage A tile (256 x 64)
    {
      const int k0 = (tid & 7) * 8;
#pragma unroll
      for (int it = 0; it < 8; ++it) {
        int m = (tid >> 3) + it * 32;
        f32x4 v = *reinterpret_cast<const f32x4*>(Ab + (long)m * ldA + kt + k0);
        int byte = m * 128 + ((k0 * 2) ^ swz(m));
        *reinterpret_cast<f32x4*>(reinterpret_cast<char*>(As) + byte) = v;
      }
    }
    // stage W tile (64 x 128) transposed -> Ws[n][k], fp32 -> bf16
    {
      const int n0 = (tid & 31) * 4;
#pragma unroll
      for (int it = 0; it < 8; ++it) {
        int k = (tid >> 5) + it * 8;
        f32x4 w4 = *reinterpret_cast<const f32x4*>(Wb + (long)(kt + k) * N + n0);
#pragma unroll
        for (int j = 0; j < 4; ++j) {
          int n = n0 + j;
          int byte = n * 128 + ((k * 2) ^ swz(n));
          *reinterpret_cast<unsigned short*>(reinterpret_cast<char*>(Ws) + byte) = f2bf(w4[j]);
        }
      }
    }
    __syncthreads();
#pragma unroll
    for (int ks = 0; ks < 2; ++ks) {
      const int kb = ks * 32 + ((lane >> 4) * 8);
      bf8 a[4], b[8];
#pragma unroll
      for (int mi = 0; mi < 4; ++mi) {
        int row = wrow + mi * 16 + (lane & 15);
        int byte = row * 128 + ((kb * 2) ^ swz(row));
        a[mi] = *reinterpret_cast<const bf8*>(reinterpret_cast<const char*>(As) + byte);
      }
#pragma unroll
      for (int ni = 0; ni < 8; ++ni) {
        int n = ni * 16 + (lane & 15);
        int byte = n * 128 + ((kb * 2) ^ swz(n));
        b[ni] = *reinterpret_cast<const bf8*>(reinterpret_cast<const char*>(Ws) + byte);
      }
#pragma unroll
      for (int mi = 0; mi < 4; ++mi)
#pragma unroll
        for (int ni = 0; ni < 8; ++ni)
          acc[mi][ni] = __builtin_amdgcn_mfma_f32_16x16x32_bf16(a[mi], b[ni], acc[mi][ni], 0, 0, 0);
    }
    __syncthreads();
  }
  // epilogue: C/D layout col=lane&15, row=(lane>>4)*4+reg
#pragma unroll
  for (int mi = 0; mi < 4; ++mi)
#pragma unroll
    for (int ni = 0; ni < 8; ++ni)
#pragma unroll
      for (int r = 0; r < 4; ++r) {
        int m = wrow + mi * 16 + (lane >> 4) * 4 + r;
        int n = n0blk + ni * 16 + (lane & 15);
        long off = ((long)m * 128 + t) * N + n;
        float v = acc[mi][ni][r];
        if constexpr (OUT_BF16) reinterpret_cast<unsigned short*>(C)[off] = f2bf(v);
        else reinterpret_cast<float*>(C)[off] = v;
      }
}

// ---------------------------------------------------------------------------
// fp32 -> bf16 convert (X)
// ---------------------------------------------------------------------------
__global__ __launch_bounds__(256)
void cvt_bf(const float* __restrict__ in, unsigned short* __restrict__ out, long n)
{
  long i = ((long)blockIdx.x * 256 + threadIdx.x) * 8;
  if (i >= n) return;
  f32x4 a = *reinterpret_cast<const f32x4*>(in + i);
  f32x4 b = *reinterpret_cast<const f32x4*>(in + i + 4);
  u16x4 w0, w1;
#pragma unroll
  for (int j = 0; j < 4; ++j) { w0[j] = f2bf(a[j]); w1[j] = f2bf(b[j]); }
  *reinterpret_cast<u16x4*>(out + i) = w0;
  *reinterpret_cast<u16x4*>(out + i + 4) = w1;
}

// ---------------------------------------------------------------------------
// v (B,T,H*256) -> vT (B*H, 256, 128)   [so attention stages vT coalesced]
// ---------------------------------------------------------------------------
__global__ __launch_bounds__(256)
void trans_v(const unsigned short* __restrict__ vb, unsigned short* __restrict__ vT)
{
  const int bh = blockIdx.y;
  const int b = bh >> 3, h = bh & 7;
  const int tile = blockIdx.x;   // 0..31
  const int tt = tile >> 3;      // t-tile (4)
  const int td = tile & 7;       // d-tile (8)
  __shared__ unsigned short sm[32][33];
  const int rloc = threadIdx.x >> 3;
  const int q4 = (threadIdx.x & 7) * 4;
  {
    long off = ((long)b * 128 + tt * 32 + rloc) * 2048 + h * 256 + td * 32 + q4;
    u16x4 v = *reinterpret_cast<const u16x4*>(vb + off);
#pragma unroll
    for (int j = 0; j < 4; ++j) sm[rloc][q4 + j] = v[j];
  }
  __syncthreads();
  {
    u16x4 w;
#pragma unroll
    for (int j = 0; j < 4; ++j) w[j] = sm[q4 + j][rloc];
    long off = ((long)bh * 256 + td * 32 + rloc) * 128 + tt * 32 + q4;
    *reinterpret_cast<u16x4*>(vT + off) = w;
  }
}

// ---------------------------------------------------------------------------
// Fused attention for one (b,h): S=q k^T/sqrt(32) (regs), wave-parallel
// softmax, P@v via LDS (P per-wave region, v in 2 s-chunks), out -> cat bf16.
// ---------------------------------------------------------------------------
__global__ __launch_bounds__(256)
void attn_k(const unsigned short* __restrict__ qg, const unsigned short* __restrict__ kg,
            const unsigned short* __restrict__ vT, unsigned short* __restrict__ cat)
{
  const int h = blockIdx.x, b = blockIdx.y;
  const int tid = threadIdx.x, lane = tid & 63, wv = tid >> 6;
  const int wrow = wv * 32;

  __shared__ short ps[128 * 128];  // P [t][s] swizzled, 32KB (per-wave 8KB regions)
  __shared__ short vs[256 * 64];   // vT chunk [d][s_local] swizzled, 32KB

  const long qkBase = ((long)b * 128) * 256 + h * 32;
  const long vBase = ((long)(b * 8 + h)) * 256 * 128;
  const int kb_ = (lane >> 4) * 8;

  // stage vs chunk 0 (s 0..63)
  {
    const int s0 = (tid & 7) * 8;
#pragma unroll
    for (int it = 0; it < 8; ++it) {
      int d = (tid >> 3) + it * 32;
      f32x4 v = *reinterpret_cast<const f32x4*>(vT + vBase + (long)d * 128 + s0);
      int byte = d * 128 + ((s0 * 2) ^ swz(d));
      *reinterpret_cast<f32x4*>(reinterpret_cast<char*>(vs) + byte) = v;
    }
  }

  // S = q k^T  (q/k frags straight from global; AE=32 = one MFMA K-step)
  f32x4 sacc[2][8];
#pragma unroll
  for (int mi = 0; mi < 2; ++mi)
#pragma unroll
    for (int c = 0; c < 8; ++c) sacc[mi][c] = f32x4{0.f, 0.f, 0.f, 0.f};
  bf8 aq[2];
#pragma unroll
  for (int mi = 0; mi < 2; ++mi) {
    int row = wrow + mi * 16 + (lane & 15);
    aq[mi] = *reinterpret_cast<const bf8*>(qg + qkBase + (long)row * 256 + kb_);
  }
#pragma unroll
  for (int ni = 0; ni < 8; ++ni) {
    int s = ni * 16 + (lane & 15);
    bf8 bk = *reinterpret_cast<const bf8*>(kg + qkBase + (long)s * 256 + kb_);
#pragma unroll
    for (int mi = 0; mi < 2; ++mi)
      sacc[mi][ni] = __builtin_amdgcn_mfma_f32_16x16x32_bf16(aq[mi], bk, sacc[mi][ni], 0, 0, 0);
  }

  // wave-parallel softmax; P written unnormalized (divide after PV)
  const float scale = 0.17677669529663687f;  // 1/sqrt(32)
  float sinv[2][4];
#pragma unroll
  for (int mi = 0; mi < 2; ++mi)
#pragma unroll
    for (int r = 0; r < 4; ++r) {
      int row = wrow + mi * 16 + (lane >> 4) * 4 + r;
      float vv[8];
      float mx = -1e30f;
#pragma unroll
      for (int c = 0; c < 8; ++c) { vv[c] = sacc[mi][c][r] * scale; mx = fmaxf(mx, vv[c]); }
#pragma unroll
      for (int mm = 1; mm < 16; mm <<= 1) mx = fmaxf(mx, __shfl_xor(mx, mm, 64));
      float s_ = 0.f;
#pragma unroll
      for (int c = 0; c < 8; ++c) { vv[c] = __expf(vv[c] - mx); s_ += vv[c]; }
#pragma unroll
      for (int mm = 1; mm < 16; mm <<= 1) s_ += __shfl_xor(s_, mm, 64);
      sinv[mi][r] = 1.0f / s_;
#pragma unroll
      for (int c = 0; c < 8; ++c) {
        int col = c * 16 + (lane & 15);
        int byte = row * 256 + ((col * 2) ^ swz(row));
        *reinterpret_cast<unsigned short*>(reinterpret_cast<char*>(ps) + byte) = f2bf(vv[c]);
      }
    }

  // PV over two 64-wide s-chunks
  f32x4 oacc[2][16];
#pragma unroll
  for (int mi = 0; mi < 2; ++mi)
#pragma unroll
    for (int c = 0; c < 16; ++c) oacc[mi][c] = f32x4{0.f, 0.f, 0.f, 0.f};

#pragma unroll 1
  for (int cs = 0; cs < 2; ++cs) {
    if (cs == 1) {
      __syncthreads();  // all waves done with vs chunk 0
      const int s0 = (tid & 7) * 8;
#pragma unroll
      for (int it = 0; it < 8; ++it) {
        int d = (tid >> 3) + it * 32;
        f32x4 v = *reinterpret_cast<const f32x4*>(vT + vBase + (long)d * 128 + 64 + s0);
        int byte = d * 128 + ((s0 * 2) ^ swz(d));
        *reinterpret_cast<f32x4*>(reinterpret_cast<char*>(vs) + byte) = v;
      }
    }
    __syncthreads();  // vs chunk staged
#pragma unroll
    for (int kst = 0; kst < 2; ++kst) {
      int kloc = kst * 32 + kb_;
      int kglob = cs * 64 + kloc;
      bf8 ap[2];
#pragma unroll
      for (int mi = 0; mi < 2; ++mi) {
        int row = wrow + mi * 16 + (lane & 15);
        int byte = row * 256 + ((kglob * 2) ^ swz(row));
        ap[mi] = *reinterpret_cast<const bf8*>(reinterpret_cast<const char*>(ps) + byte);
      }
#pragma unroll
      for (int c = 0; c < 16; ++c) {
        int d = c * 16 + (lane & 15);
        int byte = d * 128 + ((kloc * 2) ^ swz(d));
        bf8 bv = *reinterpret_cast<const bf8*>(reinterpret_cast<const char*>(vs) + byte);
#pragma unroll
        for (int mi = 0; mi < 2; ++mi)
          oacc[mi][c] = __builtin_amdgcn_mfma_f32_16x16x32_bf16(ap[mi], bv, oacc[mi][c], 0, 0, 0);
      }
    }
  }

  // write cat[b,t,h*256+d] = out/row_sum (bf16)
#pragma unroll
  for (int mi = 0; mi < 2; ++mi)
#pragma unroll
    for (int c = 0; c < 16; ++c)
#pragma unroll
      for (int r = 0; r < 4; ++r) {
        int tt = wrow + mi * 16 + (lane >> 4) * 4 + r;
        int d = c * 16 + (lane & 15);
        float v = oacc[mi][c][r] * sinv[mi][r];
        long off = ((long)b * 128 + tt) * 2048 + h * 256 + d;
        cat[off] = f2bf(v);
      }
}

// ---------------------------------------------------------------------------
// LayerNorm(a+b) with gamma/beta; optionally also write bf16 copy.
// One wave per 256-wide row; 4 rows per block.
// ---------------------------------------------------------------------------
template<bool WB>
__global__ __launch_bounds__(256)
void ln_k(const float* __restrict__ a, const float* __restrict__ bsrc,
          const float* __restrict__ gamma, const float* __restrict__ beta,
          float* __restrict__ of, unsigned short* __restrict__ ob)
{
  const int row = blockIdx.x * 4 + (threadIdx.x >> 6);
  const int lane = threadIdx.x & 63;
  const long base = (long)row * 256 + lane * 4;
  f32x4 xa = *reinterpret_cast<const f32x4*>(a + base);
  f32x4 xb = *reinterpret_cast<const f32x4*>(bsrc + base);
  f32x4 x = xa + xb;
  float s = x[0] + x[1] + x[2] + x[3];
  float s2 = x[0] * x[0] + x[1] * x[1] + x[2] * x[2] + x[3] * x[3];
#pragma unroll
  for (int mm = 1; mm < 64; mm <<= 1) { s += __shfl_xor(s, mm, 64); s2 += __shfl_xor(s2, mm, 64); }
  float mean = s * (1.f / 256.f);
  float var = fmaxf(s2 * (1.f / 256.f) - mean * mean, 0.f);
  float inv = rsqrtf(var + 1e-5f);
  f32x4 g = *reinterpret_cast<const f32x4*>(gamma + lane * 4);
  f32x4 be = *reinterpret_cast<const f32x4*>(beta + lane * 4);
  f32x4 y;
#pragma unroll
  for (int j = 0; j < 4; ++j) y[j] = (x[j] - mean) * inv * g[j] + be[j];
  *reinterpret_cast<f32x4*>(of + base) = y;
  if constexpr (WB) {
    u16x4 w;
#pragma unroll
    for (int j = 0; j < 4; ++j) w[j] = f2bf(y[j]);
    *reinterpret_cast<u16x4*>(ob + base) = w;
  }
}

// ---------------------------------------------------------------------------
// hidden = silu(gate) * up  (bf16 in/out)
// ---------------------------------------------------------------------------
__global__ __launch_bounds__(256)
void silu_k(const unsigned short* __restrict__ g, const unsigned short* __restrict__ u,
            unsigned short* __restrict__ o, long n)
{
  long i = ((long)blockIdx.x * 256 + threadIdx.x) * 8;
  if (i >= n) return;
  u16x4 g0 = *reinterpret_cast<const u16x4*>(g + i);
  u16x4 g1 = *reinterpret_cast<const u16x4*>(g + i + 4);
  u16x4 u0 = *reinterpret_cast<const u16x4*>(u + i);
  u16x4 u1 = *reinterpret_cast<const u16x4*>(u + i + 4);
  u16x4 o0, o1;
#pragma unroll
  for (int j = 0; j < 4; ++j) {
    float gg = bf2f(g0[j]), uu = bf2f(u0[j]);
    o0[j] = f2bf(gg / (1.f + __expf(-gg)) * uu);
    gg = bf2f(g1[j]); uu = bf2f(u1[j]);
    o1[j] = f2bf(gg / (1.f + __expf(-gg)) * uu);
  }
  *reinterpret_cast<u16x4*>(o + i) = o0;
  *reinterpret_cast<u16x4*>(o + i + 4) = o1;
}

// ---------------------------------------------------------------------------
// Workspace layout (total 304 MiB; lifetime-based reuse):
//   [0,16)   Xb        [16,32) qb       [32,48) kb
//   regA = ws+48MiB, 128MiB:  vb  ->  cat  ->  gate(32)|up(32)|hid(32)
//   regB = ws+176MiB, 128MiB: vT  ->  attnp(32)|x1f(32)|x1b(16)|ffn(32)
// NOTE (round-1 bug): gate/up/hid are (B,T,512) = 16.8M elem = 32MiB EACH,
// not 16MiB — the old layout overlapped them, corrupting batch b>=128.
// ---------------------------------------------------------------------------
extern "C" void kernel_launch(void* const* d_in, const int* in_sizes, int n_in,
                              void* d_out, int out_size, void* d_ws, size_t ws_size,
                              hipStream_t stream)
{
  const float* X  = (const float*)d_in[0];
  const float* Qw = (const float*)d_in[1];
  const float* Kw = (const float*)d_in[2];
  const float* Vw = (const float*)d_in[3];
  const float* Ow = (const float*)d_in[4];
  const float* Wg = (const float*)d_in[5];
  const float* Wu = (const float*)d_in[6];
  const float* Wd = (const float*)d_in[7];
  const float* g1 = (const float*)d_in[8];
  const float* b1 = (const float*)d_in[9];
  const float* g2 = (const float*)d_in[10];
  const float* b2 = (const float*)d_in[11];

  char* ws = (char*)d_ws;
  const size_t MiB = 1048576;
  unsigned short* Xb = (unsigned short*)(ws);
  unsigned short* qb = (unsigned short*)(ws + 16 * MiB);
  unsigned short* kb = (unsigned short*)(ws + 32 * MiB);
  char* regA = ws + 48 * MiB;    // 128 MiB
  char* regB = regA + 128 * MiB; // 128 MiB

  unsigned short* vb    = (unsigned short*)regA;            // dead after trans_v
  unsigned short* vT    = (unsigned short*)regB;            // dead after attn_k
  unsigned short* cat   = (unsigned short*)regA;            // attn out (vb dead)
  float*          attnp = (float*)(regB);                   // O-proj out (vT dead)
  float*          x1f   = (float*)(regB + 32 * MiB);
  unsigned short* x1b   = (unsigned short*)(regB + 64 * MiB);
  unsigned short* gateb = (unsigned short*)(regA);          // cat dead after O-proj
  unsigned short* upb   = (unsigned short*)(regA + 32 * MiB);
  unsigned short* hidb  = (unsigned short*)(regA + 64 * MiB);
  float*          ffn   = (float*)(regB + 80 * MiB);
  float* out = (float*)d_out;

  dim3 blk(256);
  cvt_bf<<<dim3(4096), blk, 0, stream>>>(X, Xb, (long)8388608);
  gemm_tk<true><<<dim3(2, 128), blk, 0, stream>>>(Xb, Qw, (void*)qb, 256, 256);
  gemm_tk<true><<<dim3(2, 128), blk, 0, stream>>>(Xb, Kw, (void*)kb, 256, 256);
  gemm_tk<true><<<dim3(16, 128), blk, 0, stream>>>(Xb, Vw, (void*)vb, 256, 2048);
  trans_v<<<dim3(32, 2048), blk, 0, stream>>>(vb, vT);
  attn_k<<<dim3(8, 256), blk, 0, stream>>>(qb, kb, vT, cat);
  gemm_tk<false><<<dim3(2, 128), blk, 0, stream>>>(cat, Ow, (void*)attnp, 2048, 256);
  ln_k<true><<<dim3(8192), blk, 0, stream>>>(X, attnp, g1, b1, x1f, x1b);
  gemm_tk<true><<<dim3(4, 128), blk, 0, stream>>>(x1b, Wg, (void*)gateb, 256, 512);
  gemm_tk<true><<<dim3(4, 128), blk, 0, stream>>>(x1b, Wu, (void*)upb, 256, 512);
  silu_k<<<dim3(8192), blk, 0, stream>>>(gateb, upb, hidb, (long)16777216);
  gemm_tk<false><<<dim3(2, 128), blk, 0, stream>>>(hidb, Wd, (void*)ffn, 512, 256);
  ln_k<false><<<dim3(8192), blk, 0, stream>>>(x1f, ffn, g2, b2, out, (unsigned short*)nullptr);
}